// Round 12
// baseline (3842.526 us; speedup 1.0000x reference)
//
#include <hip/hip_runtime.h>
#include <math.h>

#define BB   64
#define TT   256
#define DIN  512
#define HH   1024
#define NBLK 256

typedef short  bf16x8 __attribute__((ext_vector_type(8)));
typedef float  f32x4  __attribute__((ext_vector_type(4)));

// ---- ws layout (bytes) ----
// xb  : bf16 [256 t][64 b][512 k]  16,777,216
// hb  : bf16 [2][64 b][1024 j]        262,144
// bar : u32 barrier counter                 4
#define XB_OFF  0
#define HB_OFF  16777216
#define BAR_OFF (16777216 + 262144)

__device__ __forceinline__ float sig_(float x) { return 1.f / (1.f + expf(-x)); }

__device__ __forceinline__ unsigned short f2b(float f) {
    union { float f; unsigned u; } v; v.f = f;
    return (unsigned short)((v.u + 0x7FFF + ((v.u >> 16) & 1)) >> 16);   // RNE
}

__device__ __forceinline__ bf16x8 pack8(const float* p) {
    union { unsigned short s[8]; bf16x8 v; } u;
#pragma unroll
    for (int e = 0; e < 8; ++e) u.s[e] = f2b(p[e]);
    return u.v;
}

// ---- convert x: xb[t][b][k] = bf16(x[b][t][k])  (verified round 8) ----
__global__ __launch_bounds__(256) void conv_x(
    const float* __restrict__ x, unsigned short* __restrict__ xb)
{
    int gid = blockIdx.x * 256 + threadIdx.x;      // 1,048,576 granules of 8
    int t   = gid >> 12;
    int rem = gid & 4095;
    int b   = rem >> 6;
    int kg  = rem & 63;
    const float* src = x + (size_t)b * (TT * DIN) + (size_t)t * DIN + kg * 8;
    float tmp[8];
    *(float4*)(tmp)     = *(const float4*)(src);
    *(float4*)(tmp + 4) = *(const float4*)(src + 4);
    unsigned short o[8];
#pragma unroll
    for (int e = 0; e < 8; ++e) o[e] = f2b(tmp[e]);
    *(uint4*)(xb + (size_t)t * (BB * DIN) + (size_t)b * DIN + kg * 8) = *(const uint4*)o;
}

// ws is re-poisoned 0xAA before every timed launch: counter MUST be zeroed each call.
__global__ void init_bar(unsigned* bar) { if (threadIdx.x == 0) *bar = 0u; }

// ---- persistent LSTM: all 256 timesteps in ONE plain launch ----
// grid 256 x 256. Block owns h-cols [4*blk,4*blk+4) => 16 gate cols. Wave wv =
// M-tile (batches 16wv..16wv+15). Fragment maps identical to the HW-verified
// round-8 kernel. Weights: 48 bf16x8 frags = 192 VGPRs/lane, loaded once.
// c-state: 1 reg/thread. h: double-buffered bf16 hb[2][64][1024].
// Grid sync: software monotonic-counter barrier (release-add / relaxed-spin +
// acquire). <=2 blocks/CU occupancy and grid=256 => all blocks co-resident =>
// no deadlock. x-part MFMAs run BEFORE the wait (depend only on xb) to hide
// barrier latency; only the h-part waits on h(t-1).
__global__ __launch_bounds__(256, 1) void lstm_all(
    const float* __restrict__ wih, const float* __restrict__ whh,
    const float* __restrict__ bih, const float* __restrict__ bhh,
    const unsigned short* __restrict__ xb, unsigned short* __restrict__ hb,
    unsigned* bar, float* __restrict__ out)
{
    __shared__ float scr[4][16][17];   // [wave][m][c], +1 pad

    const int tid  = threadIdx.x;
    const int lane = tid & 63;
    const int wv   = tid >> 6;
    const int lo   = lane & 15;        // A row (m) / B col (c) selector
    const int hi   = lane >> 4;        // k-group selector

    const int gq = lo >> 2;            // gate for this lane's B column
    const int jo = lo & 3;
    const int j0 = blockIdx.x * 4;
    const int n  = gq * HH + j0 + jo;

    const int b    = 16 * wv + lo;     // A batch row (K-loop role)
    const int bidx = 16 * wv + lo;     // epilogue batch
    const int jj   = j0 + hi;          // epilogue h column

    // ---- one-time: weights -> registers (48 bf16x8 frags = 192 VGPRs) ----
    const float* wihrow = wih + (size_t)n * DIN;
    const float* whhrow = whh + (size_t)n * HH;
    bf16x8 wx[16], wh[32];
#pragma unroll
    for (int kk = 0; kk < 16; ++kk) {
        const int k = kk * 32 + hi * 8;
        float tmp[8];
        *(float4*)(tmp)     = *(const float4*)(wihrow + k);
        *(float4*)(tmp + 4) = *(const float4*)(wihrow + k + 4);
        wx[kk] = pack8(tmp);
    }
#pragma unroll
    for (int kk = 0; kk < 32; ++kk) {
        const int k = kk * 32 + hi * 8;
        float tmp[8];
        *(float4*)(tmp)     = *(const float4*)(whhrow + k);
        *(float4*)(tmp + 4) = *(const float4*)(whhrow + k + 4);
        wh[kk] = pack8(tmp);
    }
    const float bias = bih[n] + bhh[n];
    float creg = 0.f;                  // c[jj][bidx], step-invariant mapping

    for (int t = 0; t < TT; ++t) {
        f32x4 accA = { bias, bias, bias, bias };
        f32x4 accB = { 0.f, 0.f, 0.f, 0.f };

        // ---- x part first: depends only on read-only xb, hides barrier wait ----
        const unsigned short* xrow = xb + (size_t)t * (BB * DIN) + (size_t)b * DIN;
#pragma unroll
        for (int kk = 0; kk < 16; kk += 2) {
            bf16x8 a0 = *(const bf16x8*)(xrow + kk * 32 + hi * 8);
            bf16x8 a1 = *(const bf16x8*)(xrow + (kk + 1) * 32 + hi * 8);
            accA = __builtin_amdgcn_mfma_f32_16x16x32_bf16(a0, wx[kk],     accA, 0, 0, 0);
            accB = __builtin_amdgcn_mfma_f32_16x16x32_bf16(a1, wx[kk + 1], accB, 0, 0, 0);
        }

        // ---- wait for h(t-1) from all blocks, then h part ----
        if (t > 0) {
            if (tid == 0) {
                const unsigned target = (unsigned)t * NBLK;
                while (__hip_atomic_load(bar, __ATOMIC_RELAXED, __HIP_MEMORY_SCOPE_AGENT) < target)
                    __builtin_amdgcn_s_sleep(4);
                (void)__hip_atomic_load(bar, __ATOMIC_ACQUIRE, __HIP_MEMORY_SCOPE_AGENT);
            }
            __syncthreads();   // all threads held until caches invalidated

            const unsigned short* hrow = hb + (size_t)((t - 1) & 1) * (BB * HH) + (size_t)b * HH;
#pragma unroll
            for (int kk = 0; kk < 32; kk += 2) {
                bf16x8 a0 = *(const bf16x8*)(hrow + kk * 32 + hi * 8);
                bf16x8 a1 = *(const bf16x8*)(hrow + (kk + 1) * 32 + hi * 8);
                accA = __builtin_amdgcn_mfma_f32_16x16x32_bf16(a0, wh[kk],     accA, 0, 0, 0);
                accB = __builtin_amdgcn_mfma_f32_16x16x32_bf16(a1, wh[kk + 1], accB, 0, 0, 0);
            }
        }
        f32x4 acc = accA + accB;

        // ---- epilogue: transpose via LDS (intra-wave), pointwise, state update ----
#pragma unroll
        for (int r = 0; r < 4; ++r)
            scr[wv][4 * hi + r][lo] = acc[r];
        __syncthreads();

        float vi = scr[wv][lo][ 0 + hi];
        float vf = scr[wv][lo][ 4 + hi];
        float vg = scr[wv][lo][ 8 + hi];
        float vo = scr[wv][lo][12 + hi];

        float i_t = sig_(vi);
        float f_t = sig_(vf);
        float g_t = tanhf(vg);
        float o_t = sig_(vo);
        float cn  = fmaf(f_t, creg, i_t * g_t);
        creg = cn;
        float hn = o_t * tanhf(cn);

        out[(size_t)bidx * (TT * HH) + (size_t)t * HH + jj] = hn;
        hb[(size_t)(t & 1) * (BB * HH) + (size_t)bidx * HH + jj] = f2b(hn);

        // arrive: barrier drains each wave's stores; release-add flushes L2 so
        // hb is visible device-wide before the counter increments
        __syncthreads();
        if (tid == 0)
            __hip_atomic_fetch_add(bar, 1u, __ATOMIC_RELEASE, __HIP_MEMORY_SCOPE_AGENT);
    }
}

extern "C" void kernel_launch(void* const* d_in, const int* in_sizes, int n_in,
                              void* d_out, int out_size, void* d_ws, size_t ws_size,
                              hipStream_t stream)
{
    const float* x   = (const float*)d_in[0];
    const float* wih = (const float*)d_in[1];
    const float* whh = (const float*)d_in[2];
    const float* bih = (const float*)d_in[3];
    const float* bhh = (const float*)d_in[4];
    float* out = (float*)d_out;

    char* ws = (char*)d_ws;
    unsigned short* xb = (unsigned short*)(ws + XB_OFF);
    unsigned short* hb = (unsigned short*)(ws + HB_OFF);
    unsigned*       bar = (unsigned*)(ws + BAR_OFF);

    conv_x<<<dim3(4096), dim3(256), 0, stream>>>(x, xb);
    init_bar<<<dim3(1), dim3(64), 0, stream>>>(bar);
    lstm_all<<<dim3(256), dim3(256), 0, stream>>>(wih, whh, bih, bhh, xb, hb, bar, out);
}